// Round 5
// baseline (161.060 us; speedup 1.0000x reference)
//
#include <hip/hip_runtime.h>
#include <math.h>

// Problem constants (fixed by setup_inputs): B=4096, T=512, Q=4
#define T_DIM 512
#define GAMMA_F 0.997f
#define EPS_F 1e-3f
// log2(0.997)
#define LOG2_GAMMA (-0.0043345907f)

typedef float v4f __attribute__((ext_vector_type(4)));

__device__ __forceinline__ float inv_rescale_f(float x) {
    // sign(x) * (((sqrt(1 + 4*eps*(|x|+1+eps)) - 1) / (2*eps))^2 - 1), sign(0)=0
    float s = (x > 0.f) ? 1.f : ((x < 0.f) ? -1.f : 0.f);
    float sqrt_arg = 1.f + 4.f * EPS_F * (fabsf(x) + 1.f + EPS_F);
    float q = (sqrtf(sqrt_arg) - 1.f) * (1.f / (2.f * EPS_F));
    return s * (q * q - 1.f);
}

__device__ __forceinline__ float rescale_f(float x) {
    return copysignf(sqrtf(fabsf(x) + 1.f) - 1.f, x) + EPS_F * x;
}

// One thread per (b,t), 256 threads/block => each block covers 256 consecutive
// t of ONE row (256 | 512, blocks never straddle rows). Each input element is
// loaded from global exactly once (7 VMEM/thread, all coalesced); the 5-tap
// window is served from LDS (SoA, stride-1 => 2 lanes/bank, conflict-free).
// This collapses R3's ~5 sequential global-latency rounds (VGPR=28 ceiling)
// into one load->ds_write->barrier->ds_read round.
__global__ __launch_bounds__(256) void nstep_qloss_kernel(
    const float* __restrict__ cur_q,    // (B,T,4)
    const float* __restrict__ next_q,   // (B,T,4)
    const float* __restrict__ log_p,    // (B,T)
    const float* __restrict__ reward,   // (B,T,4)
    const float* __restrict__ is_done,  // (B,T)
    const float* __restrict__ mask,     // (B,T)
    float* __restrict__ out,            // (B,T,4)
    int BT)
{
    __shared__ float s_md [260];   // m*(1-d)        at tile t + halo (clamped)
    __shared__ float s_Lmd[260];   // m*(1-d)*log_p
    __shared__ float s_rx [260];   // m*reward.x
    __shared__ float s_ry [260];
    __shared__ float s_rz [260];
    __shared__ float s_rw [260];

    int tid = threadIdx.x;
    int idx = blockIdx.x * 256 + tid;   // flat (b,t)
    int t   = idx & (T_DIM - 1);
    int base = idx - t;                 // row start (b*T)

    const v4f* rew4 = (const v4f*)reward;
    const v4f* nq4  = (const v4f*)next_q;
    const v4f* cq4  = (const v4f*)cur_q;
    v4f* out4       = (v4f*)out;

    // ---- own-element loads (1x traffic, coalesced) ----
    float m0 = mask[idx];
    float d0 = is_done[idx];
    float p0 = log_p[idx];
    v4f   r  = rew4[idx];

    // next_q at clamped i = min(t+4, 511) and cur_q at t (issued before barrier)
    int s4 = (t + 4 < T_DIM) ? t + 4 : T_DIM - 1;
    v4f nq = nq4[base + s4];
    v4f cq = cq4[idx];

    // ---- stage own element into LDS ----
    float md0  = m0 * (1.f - d0);
    float Lmd0 = md0 * p0;
    float rx0 = m0 * r.x, ry0 = m0 * r.y, rz0 = m0 * r.z, rw0 = m0 * r.w;
    s_md [tid] = md0;
    s_Lmd[tid] = Lmd0;
    s_rx [tid] = rx0;
    s_ry [tid] = ry0;
    s_rz [tid] = rz0;
    s_rw [tid] = rw0;

    // ---- halo: tile positions 256..259 (t clamped to row end) ----
    if (tid < 4) {
        int th = t + 256;                       // t0 + 256 + tid
        if (th > T_DIM - 1) th = T_DIM - 1;
        int oh = base + th;
        float mh = mask[oh];
        float dh = is_done[oh];
        float ph = log_p[oh];
        v4f   rh = rew4[oh];
        float mdh = mh * (1.f - dh);
        s_md [256 + tid] = mdh;
        s_Lmd[256 + tid] = mdh * ph;
        s_rx [256 + tid] = mh * rh.x;
        s_ry [256 + tid] = mh * rh.y;
        s_rz [256 + tid] = mh * rh.z;
        s_rw [256 + tid] = mh * rh.w;
    }
    __syncthreads();

    // tap validity (tap 0 always valid)
    float v1 = (t + 1 < T_DIM) ? 1.f : 0.f;
    float v2 = (t + 2 < T_DIM) ? 1.f : 0.f;
    float v3 = (t + 3 < T_DIM) ? 1.f : 0.f;
    float v4 = (t + 4 < T_DIM) ? 1.f : 0.f;

    const float g1 = GAMMA_F;
    const float g2 = g1 * g1;
    const float g3 = g2 * g1;
    const float g4 = g2 * g2;
    float w1 = v1 * g1, w2 = v2 * g2, w3 = v3 * g3, w4 = v4 * g4;

    // ---- windowed sums from LDS (reward pre-masked; tap 0 from registers) ----
    float a0 = rx0, a1 = ry0, a2 = rz0, a3 = rw0;
    a0 = fmaf(w1, s_rx[tid + 1], a0); a1 = fmaf(w1, s_ry[tid + 1], a1);
    a2 = fmaf(w1, s_rz[tid + 1], a2); a3 = fmaf(w1, s_rw[tid + 1], a3);
    a0 = fmaf(w2, s_rx[tid + 2], a0); a1 = fmaf(w2, s_ry[tid + 2], a1);
    a2 = fmaf(w2, s_rz[tid + 2], a2); a3 = fmaf(w2, s_rw[tid + 2], a3);
    a0 = fmaf(w3, s_rx[tid + 3], a0); a1 = fmaf(w3, s_ry[tid + 3], a1);
    a2 = fmaf(w3, s_rz[tid + 3], a2); a3 = fmaf(w3, s_rw[tid + 3], a3);
    a0 = fmaf(w4, s_rx[tid + 4], a0); a1 = fmaf(w4, s_ry[tid + 4], a1);
    a2 = fmaf(w4, s_rz[tid + 4], a2); a3 = fmaf(w4, s_rw[tid + 4], a3);

    float Ls = Lmd0;
    Ls = fmaf(w1, s_Lmd[tid + 1], Ls);
    Ls = fmaf(w2, s_Lmd[tid + 2], Ls);
    Ls = fmaf(w3, s_Lmd[tid + 3], Ls);
    Ls = fmaf(w4, s_Lmd[tid + 4], Ls);
    Ls *= GAMMA_F * (1.f / 3.f);        // extra gamma factor * inv_num_q

    // next_term: gamma^i (absolute index, faithful), i = s4; md at clamped i
    float md4 = s_md[tid + 4];          // holds m*(1-d) at min(t+4, 511)
    float coeff = exp2f((float)s4 * LOG2_GAMMA);
    float g = coeff * md4;
    float nt0 = g * inv_rescale_f(nq.x);
    float nt1 = g * inv_rescale_f(nq.y);
    float nt2 = g * inv_rescale_f(nq.z);
    float nt3 = g * inv_rescale_f(nq.w);

    // q_w = {1, 0.5, 0, 2}; inv_qw = {1, 2, 0, 0.5}
    float tgt0 = rescale_f(a0 + nt0 + 1.0f * Ls);
    float tgt1 = rescale_f(a1 + nt1 + 2.0f * Ls);
    float tgt2 = rescale_f(a2 + nt2);
    float tgt3 = rescale_f(a3 + nt3 + 0.5f * Ls);
    (void)tgt2;

    float hm = 0.5f * m0;
    float e0 = cq.x - tgt0;
    float e1 = cq.y - tgt1;
    float e3 = cq.w - tgt3;
    v4f o;
    o.x = hm * e0 * e0;
    o.y = hm * 0.5f * e1 * e1;
    o.z = 0.f;                          // q_w[2] == 0
    o.w = hm * 2.0f * e3 * e3;
    out4[idx] = o;

    (void)BT;
}

extern "C" void kernel_launch(void* const* d_in, const int* in_sizes, int n_in,
                              void* d_out, int out_size, void* d_ws, size_t ws_size,
                              hipStream_t stream) {
    const float* cur_q   = (const float*)d_in[0];
    const float* next_q  = (const float*)d_in[1];
    const float* log_p   = (const float*)d_in[2];
    const float* reward  = (const float*)d_in[3];
    const float* is_done = (const float*)d_in[4];
    const float* mask    = (const float*)d_in[5];
    float* out = (float*)d_out;

    int BT = in_sizes[2];               // B*T, divisible by 256
    int blocks = BT / 256;
    hipLaunchKernelGGL(nstep_qloss_kernel, dim3(blocks), dim3(256), 0, stream,
                       cur_q, next_q, log_p, reward, is_done, mask, out, BT);
}